// Round 3
// baseline (596.625 us; speedup 1.0000x reference)
//
#include <hip/hip_runtime.h>

// BigraphLightModel — R8: L2-local atomics via per-XCD counter partitioning.
//   R7 post-mortem: k_cnt_rank unchanged (49.5->53us) under 8x ILP/occupancy
//   restructure => bound by device-scope atomic RMW throughput (memory-side
//   coherence point; WRITE_SIZE 42MB for a 4.8MB logical write = RMW lines).
//   This round:
//    (a) cnt/deg atomics at __HIP_MEMORY_SCOPE_WORKGROUP into per-XCD copies
//        cntx[8][N]/degx[8][N]; copy chosen by s_getreg(HW_REG_XCC_ID).
//        Same-XCD blocks share one L2 => RMW atomicity holds; no cross-XCD
//        sharing => no coherence-point round trip. rank[e] = xcc<<26 | local.
//    (b) weighted degree accumulated in k_cnt_rank (float L2 atomics from w[e])
//        — removes the ev-scan deg pass.
//    (c) k_node mega-pass: 8-copy sum -> absolute CSR bases written back into
//        cntx, rsqrt(deg), row-offset scan, degree histogram. One N-sweep.
//    (d) edge normalization fused into k_fillE (dis ready) — k_val eliminated;
//        ev written once, normalized.
//    cntx/degx (12.8MB) alias x2_u's second half (dead during both builds).
//   SpMM (degree-sorted, unroll-4) untouched this round.

#define D       64
#define N_II    100000
#define N_UIU   200000
#define E_II    600000
#define E_UIU   1200000
#define N_USERS 100000

// ---------- bf16 helpers ----------
__device__ __forceinline__ unsigned short f2bf(float f) {
    unsigned u = __float_as_uint(f);
    u += 0x7fffu + ((u >> 16) & 1u);          // round-to-nearest-even
    return (unsigned short)(u >> 16);
}
__device__ __forceinline__ void bf8_fma(float acc[8], uint4 p, float v) {
    acc[0] += v * __uint_as_float(p.x << 16);
    acc[1] += v * __uint_as_float(p.x & 0xffff0000u);
    acc[2] += v * __uint_as_float(p.y << 16);
    acc[3] += v * __uint_as_float(p.y & 0xffff0000u);
    acc[4] += v * __uint_as_float(p.z << 16);
    acc[5] += v * __uint_as_float(p.z & 0xffff0000u);
    acc[6] += v * __uint_as_float(p.w << 16);
    acc[7] += v * __uint_as_float(p.w & 0xffff0000u);
}
__device__ __forceinline__ void bf8_add(float acc[8], uint4 p) {
    acc[0] += __uint_as_float(p.x << 16);
    acc[1] += __uint_as_float(p.x & 0xffff0000u);
    acc[2] += __uint_as_float(p.y << 16);
    acc[3] += __uint_as_float(p.y & 0xffff0000u);
    acc[4] += __uint_as_float(p.z << 16);
    acc[5] += __uint_as_float(p.z & 0xffff0000u);
    acc[6] += __uint_as_float(p.w << 16);
    acc[7] += __uint_as_float(p.w & 0xffff0000u);
}
__device__ __forceinline__ uint4 pack8(const float a[8]) {
    uint4 r;
    r.x = (unsigned)f2bf(a[0]) | ((unsigned)f2bf(a[1]) << 16);
    r.y = (unsigned)f2bf(a[2]) | ((unsigned)f2bf(a[3]) << 16);
    r.z = (unsigned)f2bf(a[4]) | ((unsigned)f2bf(a[5]) << 16);
    r.w = (unsigned)f2bf(a[6]) | ((unsigned)f2bf(a[7]) << 16);
    return r;
}

// ---------- CSR build ----------

// Per-XCD counting: L2-local (workgroup-scope) atomics into this XCD's copy.
// rank[e] = (xcc<<26) | rank-within-(xcc,dst). degx accumulates weighted degree.
#define CR_K 8
__global__ void k_cnt_rank(const int* __restrict__ dst, const float* __restrict__ w,
                           int* __restrict__ cntx, float* __restrict__ degx,
                           int* __restrict__ rank, int E, int N) {
    int xcc;
    asm volatile("s_getreg_b32 %0, hwreg(HW_REG_XCC_ID)" : "=s"(xcc));
    xcc &= 7;
    int*   cnt = cntx + (size_t)xcc * N;
    float* deg = degx + (size_t)xcc * N;
    int base = blockIdx.x * (blockDim.x * CR_K) + threadIdx.x;
    int d[CR_K]; float ww[CR_K];
#pragma unroll
    for (int k = 0; k < CR_K; ++k) {
        int e = base + k * blockDim.x;
        d[k]  = (e < E) ? dst[e] : 0;
        ww[k] = (e < E) ? w[e] : 0.f;
    }
#pragma unroll
    for (int k = 0; k < CR_K; ++k) {
        int e = base + k * blockDim.x;
        if (e < E) {
            int r = __hip_atomic_fetch_add(&cnt[d[k]], 1,
                                           __ATOMIC_RELAXED, __HIP_MEMORY_SCOPE_WORKGROUP);
            __hip_atomic_fetch_add(&deg[d[k]], ww[k],
                                   __ATOMIC_RELAXED, __HIP_MEMORY_SCOPE_WORKGROUP);
            rank[e] = (xcc << 26) | r;
        }
    }
}

// mega node pass: sum 8 cnt copies -> degree c; exclusive per-XCD prefix;
// row-offset scan (block scan + atomic base); dis = rsqrt(sum deg copies);
// 64-bin degree histogram (binrank); write ABSOLUTE per-XCD write bases
// back into cntx: cntx[x][i] = row_start(i) + sum_{x'<x} cnt_{x'}[i].
__global__ void k_node(int* __restrict__ cntx, const float* __restrict__ degx,
                       int2* __restrict__ rr, float* __restrict__ dis,
                       int* __restrict__ binrank, int* __restrict__ ghist,
                       int* __restrict__ gcur, int N) {
    __shared__ int sh[256];
    __shared__ int h[64], hb[64];
    __shared__ int base;
    int t = threadIdx.x;
    int i = blockIdx.x * 256 + t;
    int px[8];
    int c = 0;
    if (i < N) {
        int s = 0;
#pragma unroll
        for (int x = 0; x < 8; ++x) {
            int v = cntx[(size_t)x * N + i];
            px[x] = s; s += v;
        }
        c = s;
        float dg = 0.f;
#pragma unroll
        for (int x = 0; x < 8; ++x) dg += degx[(size_t)x * N + i];
        dis[i] = (dg > 0.f) ? rsqrtf(dg) : 0.f;
    }
    int b = (c < 63) ? c : 63;
    sh[t] = c;
    if (t < 64) h[t] = 0;
    __syncthreads();
    int rk = 0;
    if (i < N) rk = atomicAdd(&h[b], 1);
    for (int off = 1; off < 256; off <<= 1) {   // inclusive scan
        int u = (t >= off) ? sh[t - off] : 0;
        __syncthreads();
        sh[t] += u;
        __syncthreads();
    }
    if (t == 255) base = atomicAdd(gcur, sh[255]);
    if (t < 64) hb[t] = h[t] ? atomicAdd(&ghist[t], h[t]) : 0;
    __syncthreads();
    if (i < N) {
        int o = base + sh[t] - c;
        rr[i] = make_int2(o, o + c);
        binrank[i] = hb[b] + rk;
#pragma unroll
        for (int x = 0; x < 8; ++x) cntx[(size_t)x * N + i] = o + px[x];
    }
}

// exclusive scan of 64 bin counts (single wave)
__global__ void k_scan64(const int* __restrict__ ghist, int* __restrict__ gboff) {
    int l = threadIdx.x;           // 64 lanes
    int v = ghist[l];
    int s = v;
    for (int o = 1; o < 64; o <<= 1) {
        int u = __shfl_up(s, o);
        if (l >= o) s += u;
    }
    gboff[l] = s - v;
}

// edge fill + normalization fused: pos from absolute per-XCD base + local rank;
// ev value = dis[dst]*w*dis[src]. ONE scattered 8B store per edge.
#define FE_K 4
__global__ void k_fillE(const int* __restrict__ src, const int* __restrict__ dst,
                        const float* __restrict__ w, const int* __restrict__ rank,
                        const int* __restrict__ cntx /* absolute bases */,
                        const float* __restrict__ dis,
                        int2* __restrict__ ev, int E, int N) {
    int base = blockIdx.x * (blockDim.x * FE_K) + threadIdx.x;
    int d[FE_K], r[FE_K], s[FE_K]; float ww[FE_K];
#pragma unroll
    for (int k = 0; k < FE_K; ++k) {
        int e = base + k * blockDim.x;
        if (e < E) { d[k] = dst[e]; r[k] = rank[e]; s[k] = src[e]; ww[k] = w[e]; }
        else       { d[k] = 0; r[k] = 0; s[k] = 0; ww[k] = 0.f; }
    }
    int pos[FE_K]; float val[FE_K];
#pragma unroll
    for (int k = 0; k < FE_K; ++k) {
        pos[k] = cntx[(size_t)(r[k] >> 26) * N + d[k]] + (r[k] & 0x03ffffffu);
        val[k] = dis[d[k]] * ww[k] * dis[s[k]];
    }
#pragma unroll
    for (int k = 0; k < FE_K; ++k) {
        int e = base + k * blockDim.x;
        if (e < E) ev[pos[k]] = make_int2(s[k], __float_as_int(val[k]));
    }
}

// degree-sorted row permutation scatter: perm[pos]=row, rrp[pos]=rr[row]
__global__ void k_scatter(const int2* __restrict__ rr, const int* __restrict__ binrank,
                          const int* __restrict__ gboff,
                          int* __restrict__ perm, int2* __restrict__ rrp, int N) {
    int i = blockIdx.x * blockDim.x + threadIdx.x;
    if (i >= N) return;
    int2 se = rr[i];
    int c = se.y - se.x;
    int b = (c < 63) ? c : 63;
    int pos = gboff[b] + binrank[i];
    perm[pos] = i;
    rrp[pos]  = se;
}

// fp32 -> bf16 row conversion (thread = 8 dims)
__global__ void k_cvt(const float4* __restrict__ x, uint4* __restrict__ xb, int n8) {
    int i = blockIdx.x * blockDim.x + threadIdx.x;
    if (i >= n8) return;
    float4 a = x[2 * i], b = x[2 * i + 1];
    float t[8] = {a.x, a.y, a.z, a.w, b.x, b.y, b.z, b.w};
    xb[i] = pack8(t);
}

// ---------- pull SpMM: 8-lane group per row (8 rows/wave), degree-sorted ----------
__global__ void k_spmm8(const int2* __restrict__ rrp, const int* __restrict__ perm,
                        const int2* __restrict__ ev, const uint4* __restrict__ xb,
                        uint4* __restrict__ xn, int N) {
    int idx = blockIdx.x * blockDim.x + threadIdx.x;
    int vrow = idx >> 3;
    if (vrow >= N) return;
    int g = idx & 7;
    int2 se = rrp[vrow];
    int row = perm[vrow];
    float acc[8] = {0.f, 0.f, 0.f, 0.f, 0.f, 0.f, 0.f, 0.f};
    int j = se.x, e = se.y;
    for (; j + 3 < e; j += 4) {           // unroll-4: 32 gathers in flight per wave
        int2 p0 = ev[j], p1 = ev[j + 1], p2 = ev[j + 2], p3 = ev[j + 3];
        uint4 a0 = xb[p0.x * 8 + g];
        uint4 a1 = xb[p1.x * 8 + g];
        uint4 a2 = xb[p2.x * 8 + g];
        uint4 a3 = xb[p3.x * 8 + g];
        bf8_fma(acc, a0, __int_as_float(p0.y));
        bf8_fma(acc, a1, __int_as_float(p1.y));
        bf8_fma(acc, a2, __int_as_float(p2.y));
        bf8_fma(acc, a3, __int_as_float(p3.y));
    }
    for (; j < e; ++j) {
        int2 p0 = ev[j];
        uint4 a0 = xb[p0.x * 8 + g];
        bf8_fma(acc, a0, __int_as_float(p0.y));
    }
    xn[row * 8 + g] = pack8(acc);
}

// final layer, fused epilogue: res = alpha*(x0 + x1 + x2 + A*x2)
// x0 consumed in bf16. out (fp32) optional; outb (bf16) optional.
__global__ void k_spmm8_final(const int2* __restrict__ rrp, const int* __restrict__ perm,
                              const int2* __restrict__ ev, const uint4* __restrict__ x2b,
                              const uint4* __restrict__ x1b, const uint4* __restrict__ x0b,
                              float4* __restrict__ out, uint4* __restrict__ outb,
                              float alpha, int N) {
    int idx = blockIdx.x * blockDim.x + threadIdx.x;
    int vrow = idx >> 3;
    if (vrow >= N) return;
    int g = idx & 7;
    int2 se = rrp[vrow];
    int row = perm[vrow];
    float acc[8] = {0.f, 0.f, 0.f, 0.f, 0.f, 0.f, 0.f, 0.f};
    int j = se.x, e = se.y;
    for (; j + 3 < e; j += 4) {
        int2 p0 = ev[j], p1 = ev[j + 1], p2 = ev[j + 2], p3 = ev[j + 3];
        uint4 a0 = x2b[p0.x * 8 + g];
        uint4 a1 = x2b[p1.x * 8 + g];
        uint4 a2 = x2b[p2.x * 8 + g];
        uint4 a3 = x2b[p3.x * 8 + g];
        bf8_fma(acc, a0, __int_as_float(p0.y));
        bf8_fma(acc, a1, __int_as_float(p1.y));
        bf8_fma(acc, a2, __int_as_float(p2.y));
        bf8_fma(acc, a3, __int_as_float(p3.y));
    }
    for (; j < e; ++j) {
        int2 p0 = ev[j];
        uint4 a0 = x2b[p0.x * 8 + g];
        bf8_fma(acc, a0, __int_as_float(p0.y));
    }
    bf8_add(acc, x1b[row * 8 + g]);       // + x1
    bf8_add(acc, x2b[row * 8 + g]);       // + x2
    bf8_add(acc, x0b[row * 8 + g]);       // + x0 (bf16)
    float r[8];
#pragma unroll
    for (int k = 0; k < 8; ++k) r[k] = alpha * acc[k];
    if (out) {
        out[row * 16 + 2 * g]     = make_float4(r[0], r[1], r[2], r[3]);
        out[row * 16 + 2 * g + 1] = make_float4(r[4], r[5], r[6], r[7]);
    }
    if (outb) outb[row * 8 + g] = pack8(r);
}

// ---------- host-side orchestration ----------

static void build_csr(const int* src, const int* dst, const float* w, int E, int N,
                      int2* ev, int* rank, int* cntx, float* degx, int2* rr,
                      float* dis, int* gtail /* gcur|ghist[64]|gboff[64] */,
                      int* binrank, int* perm, int2* rrp, hipStream_t stream) {
    const int B = 256;
    const int nbN = (N + B - 1) / B;
    const int nbE_cr = (E + B * CR_K - 1) / (B * CR_K);
    const int nbE_fe = (E + B * FE_K - 1) / (B * FE_K);
    int* gcur  = gtail;
    int* ghist = gtail + 1;
    int* gboff = gtail + 65;
    hipMemsetAsync(cntx, 0, (size_t)16 * N * sizeof(int), stream);  // cntx+degx
    hipMemsetAsync(gtail, 0, 65 * sizeof(int), stream);             // gcur+ghist
    k_cnt_rank<<<nbE_cr, B, 0, stream>>>(dst, w, cntx, degx, rank, E, N);
    k_node    <<<nbN, B, 0, stream>>>(cntx, degx, rr, dis, binrank, ghist, gcur, N);
    k_scan64  <<<1, 64, 0, stream>>>(ghist, gboff);
    k_fillE   <<<nbE_fe, B, 0, stream>>>(src, dst, w, rank, cntx, dis, ev, E, N);
    k_scatter <<<nbN, B, 0, stream>>>(rr, binrank, gboff, perm, rrp, N);
}

extern "C" void kernel_launch(void* const* d_in, const int* in_sizes, int n_in,
                              void* d_out, int out_size, void* d_ws, size_t ws_size,
                              hipStream_t stream) {
    const float* emb_ii  = (const float*)d_in[0];
    const float* emb_uiu = (const float*)d_in[1];
    const float* w_ii    = (const float*)d_in[2];
    const float* w_uiu   = (const float*)d_in[3];
    const int*   src_ii  = (const int*)d_in[4];
    const int*   dst_ii  = src_ii + E_II;
    const int*   src_uiu = (const int*)d_in[5];
    const int*   dst_uiu = src_uiu + E_UIU;
    float*       out     = (float*)d_out;

    // workspace (~93.7 MB):
    //   xb0_u | x1_u | x2_u : 3 x N_UIU*8 uint4 (bf16 rows, 25.6MB each)
    //   ev [E_UIU int2] | rank [E_UIU int] | rr [N_UIU int2] | gtail[129] | dis | binrank
    //   cntx[8N]+degx[8N] (12.8MB max) alias x2_u's SECOND half (dead during builds:
    //   g1 uses only x2_u first half; g2's spmm writes x2_u after build completes).
    //   perm/rrp alias the rank block after k_fillE consumed it.
    uint4* xb0_u = (uint4*)d_ws;
    uint4* x1_u  = xb0_u + (size_t)N_UIU * 8;
    uint4* x2_u  = x1_u + (size_t)N_UIU * 8;
    int2*  ev    = (int2*)(x2_u + (size_t)N_UIU * 8);
    int*   rank  = (int*)(ev + E_UIU);
    int2*  rr    = (int2*)(rank + E_UIU);
    int*   gtail = (int*)(rr + N_UIU);              // gcur|ghist|gboff : 129 ints
    float* dis   = (float*)(gtail + 129);           // N_UIU floats
    int*   binrank = (int*)(dis + N_UIU);           // N_UIU ints

    int*   cntx  = (int*)(x2_u + (size_t)N_UIU * 4);   // x2_u second half (12.8MB)
    float* degx  = (float*)(cntx + (size_t)8 * N_UIU); // wait-for-size note: set per graph below

    uint4* g1_x0 = x1_u;                              // 12.8MB
    uint4* g1_x1 = x1_u + (size_t)N_II * 8;           // 12.8MB
    uint4* g1_x2 = x2_u;                              // 12.8MB (first half only)

    const int B = 256;
    const float alpha = 0.25f;   // 1/(L+1), L=3 for both graphs

    // ================= item-item graph =================
    {
        int*   cx = cntx;                             // 8*N_II ints
        float* dx = (float*)(cntx + (size_t)8 * N_II);
        int*  perm = rank + N_II;                     // aliases rank block
        int2* rrp  = (int2*)(rank + 2 * N_II);
        build_csr(src_ii, dst_ii, w_ii, E_II, N_II, ev, rank, cx, dx, rr, dis,
                  gtail, binrank, perm, rrp, stream);
        const int n8 = N_II * 8;
        const int ng = (n8 + B - 1) / B;
        uint4* hii_b = xb0_u + (size_t)N_USERS * 8;   // bf16 result -> graph2 x0 item block
        k_cvt  <<<ng, B, 0, stream>>>((const float4*)emb_ii, g1_x0, n8);
        k_spmm8<<<ng, B, 0, stream>>>(rrp, perm, ev, g1_x0, g1_x1, N_II);
        k_spmm8<<<ng, B, 0, stream>>>(rrp, perm, ev, g1_x1, g1_x2, N_II);
        k_spmm8_final<<<ng, B, 0, stream>>>(rrp, perm, ev, g1_x2, g1_x1, g1_x0,
                                            nullptr, hii_b, alpha, N_II);
    }

    // ================= user-item graph =================
    {
        int*   cx = cntx;                             // 8*N_UIU ints
        float* dx = (float*)(cntx + (size_t)8 * N_UIU);
        int*  perm = rank + N_UIU;
        int2* rrp  = (int2*)(rank + 2 * N_UIU);
        build_csr(src_uiu, dst_uiu, w_uiu, E_UIU, N_UIU, ev, rank, cx, dx, rr, dis,
                  gtail, binrank, perm, rrp, stream);
        // convert only the user half of x0; item half written bf16 by graph1 final
        const int n8u = N_USERS * 8;
        k_cvt<<<(n8u + B - 1) / B, B, 0, stream>>>((const float4*)emb_uiu, xb0_u, n8u);
        const int n8 = N_UIU * 8;
        const int ng = (n8 + B - 1) / B;
        k_spmm8<<<ng, B, 0, stream>>>(rrp, perm, ev, xb0_u, x1_u, N_UIU);
        k_spmm8<<<ng, B, 0, stream>>>(rrp, perm, ev, x1_u, x2_u, N_UIU);
        k_spmm8_final<<<ng, B, 0, stream>>>(rrp, perm, ev, x2_u, x1_u, xb0_u,
                                            (float4*)out, nullptr, alpha, N_UIU);
    }
}

// Round 4
// 480.008 us; speedup vs baseline: 1.2429x; 1.2429x over previous
//
#include <hip/hip_runtime.h>

// BigraphLightModel — R9: overlap-scheduled build (revert R8's 2x-atomic scheme).
//   R7/R8 established: scattered global atomicAdd ~20-24 G/s device-wide,
//   invariant to scope/ILP/occupancy/copies => 1 atomic/edge is a hard
//   26us(g1)+53us(g2) floor, but it leaves VALU/HBM idle (0.5%/11%).
//   This round: hide it. Grid-partitioned fused dispatches (blockIdx range
//   -> role; atomics are order-free so g2's count pass is SLICED across
//   g1's build+spmm chain):
//     F0 [cnt_g1 | cvt_g1 | cvt_g2user]
//     F1..F6 [g1 node/fillE/deg/valsc/spmm1/spmm2 | cnt_g2 slice]
//     F7 [final_g1 | node_g2]; then g2 fillE/deg/valsc/spmm chain plain.
//   scan64 folded into valsc (per-block in-wave scan of ghist[64]).
//   Dispatches 30 -> 16. g1 build block aliases x2_u 2nd half (dead till
//   g2 spmm2). SpMM kernels unchanged (degree-sorted, unroll-4, bf16).

#define D       64
#define N_II    100000
#define N_UIU   200000
#define E_II    600000
#define E_UIU   1200000
#define N_USERS 100000
#define B       256
#define CR_K    8
#define FE_K    4

// ---------- bf16 helpers ----------
__device__ __forceinline__ unsigned short f2bf(float f) {
    unsigned u = __float_as_uint(f);
    u += 0x7fffu + ((u >> 16) & 1u);          // round-to-nearest-even
    return (unsigned short)(u >> 16);
}
__device__ __forceinline__ void bf8_fma(float acc[8], uint4 p, float v) {
    acc[0] += v * __uint_as_float(p.x << 16);
    acc[1] += v * __uint_as_float(p.x & 0xffff0000u);
    acc[2] += v * __uint_as_float(p.y << 16);
    acc[3] += v * __uint_as_float(p.y & 0xffff0000u);
    acc[4] += v * __uint_as_float(p.z << 16);
    acc[5] += v * __uint_as_float(p.z & 0xffff0000u);
    acc[6] += v * __uint_as_float(p.w << 16);
    acc[7] += v * __uint_as_float(p.w & 0xffff0000u);
}
__device__ __forceinline__ void bf8_add(float acc[8], uint4 p) {
    acc[0] += __uint_as_float(p.x << 16);
    acc[1] += __uint_as_float(p.x & 0xffff0000u);
    acc[2] += __uint_as_float(p.y << 16);
    acc[3] += __uint_as_float(p.y & 0xffff0000u);
    acc[4] += __uint_as_float(p.z << 16);
    acc[5] += __uint_as_float(p.z & 0xffff0000u);
    acc[6] += __uint_as_float(p.w << 16);
    acc[7] += __uint_as_float(p.w & 0xffff0000u);
}
__device__ __forceinline__ uint4 pack8(const float a[8]) {
    uint4 r;
    r.x = (unsigned)f2bf(a[0]) | ((unsigned)f2bf(a[1]) << 16);
    r.y = (unsigned)f2bf(a[2]) | ((unsigned)f2bf(a[3]) << 16);
    r.z = (unsigned)f2bf(a[4]) | ((unsigned)f2bf(a[5]) << 16);
    r.w = (unsigned)f2bf(a[6]) | ((unsigned)f2bf(a[7]) << 16);
    return r;
}

// ================= role device functions (bid = role-local block id) =================

// count+rank over edge range [e0,e1): K=8 batched, 1 atomic/edge.
__device__ __forceinline__ void rol_cnt(int bid, const int* __restrict__ dst,
                                        int* __restrict__ cnt, int* __restrict__ rank,
                                        int e0, int e1) {
    int base = e0 + bid * (B * CR_K) + threadIdx.x;
    int d[CR_K];
#pragma unroll
    for (int k = 0; k < CR_K; ++k) {
        int e = base + k * B;
        d[k] = (e < e1) ? dst[e] : 0;
    }
#pragma unroll
    for (int k = 0; k < CR_K; ++k) {
        int e = base + k * B;
        if (e < e1) rank[e] = atomicAdd(&cnt[d[k]], 1);
    }
}

// fp32 -> bf16 row conversion (thread = 8 dims)
__device__ __forceinline__ void rol_cvt(int bid, const float4* __restrict__ x,
                                        uint4* __restrict__ xb, int n8) {
    int i = bid * B + threadIdx.x;
    if (i >= n8) return;
    float4 a = x[2 * i], b = x[2 * i + 1];
    float t[8] = {a.x, a.y, a.z, a.w, b.x, b.y, b.z, b.w};
    xb[i] = pack8(t);
}

// node pass: row-offset scan (order-free alloc) + 64-bin degree histogram + binrank
__device__ void rol_node(int bid, const int* __restrict__ cnt, int2* __restrict__ rr,
                         int* __restrict__ binrank, int* __restrict__ ghist,
                         int* __restrict__ gcur, int N) {
    __shared__ int sh[B];
    __shared__ int h[64], hb[64];
    __shared__ int sbase;
    int t = threadIdx.x;
    int i = bid * B + t;
    int c = (i < N) ? cnt[i] : 0;
    int b = (c < 63) ? c : 63;
    sh[t] = c;
    if (t < 64) h[t] = 0;
    __syncthreads();
    int rk = 0;
    if (i < N) rk = atomicAdd(&h[b], 1);
    for (int off = 1; off < B; off <<= 1) {   // inclusive scan
        int u = (t >= off) ? sh[t - off] : 0;
        __syncthreads();
        sh[t] += u;
        __syncthreads();
    }
    if (t == B - 1) sbase = atomicAdd(gcur, sh[B - 1]);
    if (t < 64) hb[t] = h[t] ? atomicAdd(&ghist[t], h[t]) : 0;
    __syncthreads();
    if (i < N) {
        int o = sbase + sh[t] - c;
        rr[i] = make_int2(o, o + c);
        binrank[i] = hb[b] + rk;
    }
}

// edge fill: coalesced reads, ONE scattered 8B store per edge (raw w payload)
__device__ __forceinline__ void rol_fillE(int bid, const int* __restrict__ src,
                                          const int* __restrict__ dst,
                                          const float* __restrict__ w,
                                          const int* __restrict__ rank,
                                          const int2* __restrict__ rr,
                                          int2* __restrict__ ev, int E) {
    int base = bid * (B * FE_K) + threadIdx.x;
    int d[FE_K], r[FE_K], s[FE_K];
    float ww[FE_K];
#pragma unroll
    for (int k = 0; k < FE_K; ++k) {
        int e = base + k * B;
        if (e < E) { d[k] = dst[e]; r[k] = rank[e]; s[k] = src[e]; ww[k] = w[e]; }
        else       { d[k] = 0; r[k] = 0; s[k] = 0; ww[k] = 0.f; }
    }
    int pos[FE_K];
#pragma unroll
    for (int k = 0; k < FE_K; ++k) pos[k] = rr[d[k]].x + r[k];
#pragma unroll
    for (int k = 0; k < FE_K; ++k) {
        int e = base + k * B;
        if (e < E) ev[pos[k]] = make_int2(s[k], __float_as_int(ww[k]));
    }
}

// weighted degree from CSR; dis = rsqrt(deg) or 0
__device__ __forceinline__ void rol_deg(int bid, const int2* __restrict__ rr,
                                        const int2* __restrict__ ev,
                                        float* __restrict__ dis, int N) {
    int i = bid * B + threadIdx.x;
    if (i >= N) return;
    int2 se = rr[i];
    float dg = 0.f;
    for (int j = se.x; j < se.y; ++j) dg += __int_as_float(ev[j].y);
    dis[i] = (dg > 0.f) ? rsqrtf(dg) : 0.f;
}

// normalize ev in place + degree-sorted permutation scatter.
// ghist[64] exclusive scan recomputed per block in wave 0 (replaces k_scan64).
__device__ void rol_valsc(int bid, const int2* __restrict__ rr, const float* __restrict__ dis,
                          const int* __restrict__ binrank, const int* __restrict__ ghist,
                          int2* __restrict__ ev, int* __restrict__ perm,
                          int2* __restrict__ rrp, int N) {
    __shared__ int sboff[64];
    int t = threadIdx.x;
    if (t < 64) {
        int v = ghist[t];
        int s = v;
        for (int o = 1; o < 64; o <<= 1) {
            int u = __shfl_up(s, o);
            if (t >= o) s += u;
        }
        sboff[t] = s - v;
    }
    __syncthreads();
    int i = bid * B + t;
    if (i >= N) return;
    int2 se = rr[i];
    float di = dis[i];
    for (int j = se.x; j < se.y; ++j) {
        int2 p = ev[j];
        ev[j].y = __float_as_int(di * __int_as_float(p.y) * dis[p.x]);
    }
    int c = se.y - se.x;
    int b = (c < 63) ? c : 63;
    int pos = sboff[b] + binrank[i];
    perm[pos] = i;
    rrp[pos]  = se;
}

// pull SpMM: 8-lane group per (degree-sorted) row, bf16 gathers, unroll-4
__device__ void rol_spmm(int bid, const int2* __restrict__ rrp, const int* __restrict__ perm,
                         const int2* __restrict__ ev, const uint4* __restrict__ xb,
                         uint4* __restrict__ xn, int N) {
    int idx = bid * B + threadIdx.x;
    int vrow = idx >> 3;
    if (vrow >= N) return;
    int g = idx & 7;
    int2 se = rrp[vrow];
    int row = perm[vrow];
    float acc[8] = {0.f, 0.f, 0.f, 0.f, 0.f, 0.f, 0.f, 0.f};
    int j = se.x, e = se.y;
    for (; j + 3 < e; j += 4) {
        int2 p0 = ev[j], p1 = ev[j + 1], p2 = ev[j + 2], p3 = ev[j + 3];
        uint4 a0 = xb[p0.x * 8 + g];
        uint4 a1 = xb[p1.x * 8 + g];
        uint4 a2 = xb[p2.x * 8 + g];
        uint4 a3 = xb[p3.x * 8 + g];
        bf8_fma(acc, a0, __int_as_float(p0.y));
        bf8_fma(acc, a1, __int_as_float(p1.y));
        bf8_fma(acc, a2, __int_as_float(p2.y));
        bf8_fma(acc, a3, __int_as_float(p3.y));
    }
    for (; j < e; ++j) {
        int2 p0 = ev[j];
        uint4 a0 = xb[p0.x * 8 + g];
        bf8_fma(acc, a0, __int_as_float(p0.y));
    }
    xn[row * 8 + g] = pack8(acc);
}

// final layer, fused epilogue: res = alpha*(x0 + x1 + x2 + A*x2), x0 bf16
__device__ void rol_final(int bid, const int2* __restrict__ rrp, const int* __restrict__ perm,
                          const int2* __restrict__ ev, const uint4* __restrict__ x2b,
                          const uint4* __restrict__ x1b, const uint4* __restrict__ x0b,
                          float4* __restrict__ out, uint4* __restrict__ outb,
                          float alpha, int N) {
    int idx = bid * B + threadIdx.x;
    int vrow = idx >> 3;
    if (vrow >= N) return;
    int g = idx & 7;
    int2 se = rrp[vrow];
    int row = perm[vrow];
    float acc[8] = {0.f, 0.f, 0.f, 0.f, 0.f, 0.f, 0.f, 0.f};
    int j = se.x, e = se.y;
    for (; j + 3 < e; j += 4) {
        int2 p0 = ev[j], p1 = ev[j + 1], p2 = ev[j + 2], p3 = ev[j + 3];
        uint4 a0 = x2b[p0.x * 8 + g];
        uint4 a1 = x2b[p1.x * 8 + g];
        uint4 a2 = x2b[p2.x * 8 + g];
        uint4 a3 = x2b[p3.x * 8 + g];
        bf8_fma(acc, a0, __int_as_float(p0.y));
        bf8_fma(acc, a1, __int_as_float(p1.y));
        bf8_fma(acc, a2, __int_as_float(p2.y));
        bf8_fma(acc, a3, __int_as_float(p3.y));
    }
    for (; j < e; ++j) {
        int2 p0 = ev[j];
        uint4 a0 = x2b[p0.x * 8 + g];
        bf8_fma(acc, a0, __int_as_float(p0.y));
    }
    bf8_add(acc, x1b[row * 8 + g]);
    bf8_add(acc, x2b[row * 8 + g]);
    bf8_add(acc, x0b[row * 8 + g]);
    float r[8];
#pragma unroll
    for (int k = 0; k < 8; ++k) r[k] = alpha * acc[k];
    if (out) {
        out[row * 16 + 2 * g]     = make_float4(r[0], r[1], r[2], r[3]);
        out[row * 16 + 2 * g + 1] = make_float4(r[4], r[5], r[6], r[7]);
    }
    if (outb) outb[row * 8 + g] = pack8(r);
}

// ================= fused dispatch kernels (blockIdx range -> role) =================

__global__ void f_cnt_cvt2(int nbA, const int* dstA, int* cntA, int* rankA, int eA,
                           int nbB, const float4* xB, uint4* xbB, int n8B,
                           const float4* xC, uint4* xbC, int n8C) {
    int b = (int)blockIdx.x;
    if (b < nbA)       { rol_cnt(b, dstA, cntA, rankA, 0, eA); return; }
    b -= nbA;
    if (b < nbB)       { rol_cvt(b, xB, xbB, n8B); return; }
    rol_cvt(b - nbB, xC, xbC, n8C);
}

__global__ void f_node_cnt(int nbA, const int* cntN, int2* rr, int* brk, int* ghist,
                           int* gcur, int N,
                           const int* dstS, int* cntS, int* rankS, int e0, int e1) {
    int b = (int)blockIdx.x;
    if (b < nbA) rol_node(b, cntN, rr, brk, ghist, gcur, N);
    else         rol_cnt(b - nbA, dstS, cntS, rankS, e0, e1);
}

__global__ void f_fillE_cnt(int nbA, const int* src, const int* dst, const float* w,
                            const int* rank, const int2* rr, int2* ev, int E,
                            const int* dstS, int* cntS, int* rankS, int e0, int e1) {
    int b = (int)blockIdx.x;
    if (b < nbA) rol_fillE(b, src, dst, w, rank, rr, ev, E);
    else         rol_cnt(b - nbA, dstS, cntS, rankS, e0, e1);
}

__global__ void f_deg_cnt(int nbA, const int2* rr, const int2* ev, float* dis, int N,
                          const int* dstS, int* cntS, int* rankS, int e0, int e1) {
    int b = (int)blockIdx.x;
    if (b < nbA) rol_deg(b, rr, ev, dis, N);
    else         rol_cnt(b - nbA, dstS, cntS, rankS, e0, e1);
}

__global__ void f_valsc_cnt(int nbA, const int2* rr, const float* dis, const int* brk,
                            const int* ghist, int2* ev, int* perm, int2* rrp, int N,
                            const int* dstS, int* cntS, int* rankS, int e0, int e1) {
    int b = (int)blockIdx.x;
    if (b < nbA) rol_valsc(b, rr, dis, brk, ghist, ev, perm, rrp, N);
    else         rol_cnt(b - nbA, dstS, cntS, rankS, e0, e1);
}

__global__ void f_spmm_cnt(int nbA, const int2* rrp, const int* perm, const int2* ev,
                           const uint4* xb, uint4* xn, int N,
                           const int* dstS, int* cntS, int* rankS, int e0, int e1) {
    int b = (int)blockIdx.x;
    if (b < nbA) rol_spmm(b, rrp, perm, ev, xb, xn, N);
    else         rol_cnt(b - nbA, dstS, cntS, rankS, e0, e1);
}

__global__ void f_final_node(int nbA, const int2* rrpA, const int* permA, const int2* evA,
                             const uint4* x2b, const uint4* x1b, const uint4* x0b,
                             float4* outA, uint4* outbA, float alpha, int NA,
                             const int* cntN, int2* rrB, int* brkB, int* ghistB,
                             int* gcurB, int NB) {
    int b = (int)blockIdx.x;
    if (b < nbA) rol_final(b, rrpA, permA, evA, x2b, x1b, x0b, outA, outbA, alpha, NA);
    else         rol_node(b - nbA, cntN, rrB, brkB, ghistB, gcurB, NB);
}

// plain single-role kernels (g2 tail)
__global__ void k_fillE(const int* src, const int* dst, const float* w, const int* rank,
                        const int2* rr, int2* ev, int E) {
    rol_fillE((int)blockIdx.x, src, dst, w, rank, rr, ev, E);
}
__global__ void k_deg(const int2* rr, const int2* ev, float* dis, int N) {
    rol_deg((int)blockIdx.x, rr, ev, dis, N);
}
__global__ void k_valsc(const int2* rr, const float* dis, const int* brk, const int* ghist,
                        int2* ev, int* perm, int2* rrp, int N) {
    rol_valsc((int)blockIdx.x, rr, dis, brk, ghist, ev, perm, rrp, N);
}
__global__ void k_spmm8(const int2* rrp, const int* perm, const int2* ev,
                        const uint4* xb, uint4* xn, int N) {
    rol_spmm((int)blockIdx.x, rrp, perm, ev, xb, xn, N);
}
__global__ void k_spmm8_final(const int2* rrp, const int* perm, const int2* ev,
                              const uint4* x2b, const uint4* x1b, const uint4* x0b,
                              float4* out, uint4* outb, float alpha, int N) {
    rol_final((int)blockIdx.x, rrp, perm, ev, x2b, x1b, x0b, out, outb, alpha, N);
}

// ================= host-side orchestration =================

static inline int nbx(int work, int per) { return (work + per - 1) / per; }

extern "C" void kernel_launch(void* const* d_in, const int* in_sizes, int n_in,
                              void* d_out, int out_size, void* d_ws, size_t ws_size,
                              hipStream_t stream) {
    const float* emb_ii  = (const float*)d_in[0];
    const float* emb_uiu = (const float*)d_in[1];
    const float* w_ii    = (const float*)d_in[2];
    const float* w_uiu   = (const float*)d_in[3];
    const int*   src_ii  = (const int*)d_in[4];
    const int*   dst_ii  = src_ii + E_II;
    const int*   src_uiu = (const int*)d_in[5];
    const int*   dst_uiu = src_uiu + E_UIU;
    float*       out     = (float*)d_out;

    // ---- workspace (~95.2 MB), same footprint as R7 ----
    // xb0_u | x1_u | x2_u : 3 x N_UIU*8 uint4 (25.6MB each)
    // g1 build block (9.2MB) aliases x2_u SECOND half (12.8MB, dead until g2 spmm2)
    // g2 build block (18.4MB) in the tail after x2_u.
    uint4* xb0_u = (uint4*)d_ws;
    uint4* x1_u  = xb0_u + (size_t)N_UIU * 8;
    uint4* x2_u  = x1_u + (size_t)N_UIU * 8;

    // g1 block in x2_u second half
    int2*  ev1   = (int2*)(x2_u + (size_t)N_II * 8);
    int*   rank1 = (int*)(ev1 + E_II);
    int2*  rr1   = (int2*)(rank1 + E_II);
    int*   cnt1  = (int*)(rr1 + N_II);
    int*   gt1   = cnt1 + N_II;                 // gcur | ghist[64]
    float* dis1  = (float*)(gt1 + 65);
    int*   brk1  = (int*)(dis1 + N_II);
    int*   perm1 = rank1;                       // alias post-fillE
    int2*  rrp1  = (int2*)(rank1 + N_II);

    // g2 block in the tail
    int2*  ev2   = (int2*)(x2_u + (size_t)N_UIU * 8);
    int*   rank2 = (int*)(ev2 + E_UIU);
    int2*  rr2   = (int2*)(rank2 + E_UIU);
    int*   cnt2  = (int*)(rr2 + N_UIU);
    int*   gt2   = cnt2 + N_UIU;                // gcur | ghist[64]
    float* dis2  = (float*)(gt2 + 65);
    int*   brk2  = (int*)(dis2 + N_UIU);
    int*   perm2 = rank2;
    int2*  rrp2  = (int2*)(rank2 + N_UIU);

    uint4* g1_x0 = x1_u;                         // 12.8MB (x1_u 1st half)
    uint4* g1_x1 = x1_u + (size_t)N_II * 8;      // 12.8MB (x1_u 2nd half)
    uint4* g1_x2 = x2_u;                         // 12.8MB (x2_u 1st half)
    uint4* hii_b = xb0_u + (size_t)N_USERS * 8;  // g2 x0 item half

    const float alpha = 0.25f;    // 1/(L+1), L=3 both graphs

    hipMemsetAsync(cnt1, 0, ((size_t)N_II + 65) * sizeof(int), stream);
    hipMemsetAsync(cnt2, 0, ((size_t)N_UIU + 65) * sizeof(int), stream);

    // g2 cnt slice boundaries (sum = E_UIU), sized to host-stage capacity
    const int s[7] = {0, 128000, 320000, 448000, 640000, 920000, E_UIU};

    const int nbCnt1 = nbx(E_II, B * CR_K);
    const int nbCvt1 = nbx(N_II * 8, B);
    const int nbCvt2 = nbx(N_USERS * 8, B);
    const int nbN1   = nbx(N_II, B);
    const int nbF1   = nbx(E_II, B * FE_K);
    const int nbS1   = nbx(N_II * 8, B);
    const int nbN2   = nbx(N_UIU, B);
    const int nbF2   = nbx(E_UIU, B * FE_K);
    const int nbS2   = nbx(N_UIU * 8, B);

    // F0: g1 count + both bf16 conversions
    f_cnt_cvt2<<<nbCnt1 + nbCvt1 + nbCvt2, B, 0, stream>>>(
        nbCnt1, dst_ii, cnt1, rank1, E_II,
        nbCvt1, (const float4*)emb_ii, g1_x0, N_II * 8,
        (const float4*)emb_uiu, xb0_u, N_USERS * 8);

    // F1: g1 node | cnt2 slice 0
    f_node_cnt<<<nbN1 + nbx(s[1] - s[0], B * CR_K), B, 0, stream>>>(
        nbN1, cnt1, rr1, brk1, gt1 + 1, gt1, N_II,
        dst_uiu, cnt2, rank2, s[0], s[1]);

    // F2: g1 fillE | cnt2 slice 1
    f_fillE_cnt<<<nbF1 + nbx(s[2] - s[1], B * CR_K), B, 0, stream>>>(
        nbF1, src_ii, dst_ii, w_ii, rank1, rr1, ev1, E_II,
        dst_uiu, cnt2, rank2, s[1], s[2]);

    // F3: g1 deg | cnt2 slice 2
    f_deg_cnt<<<nbN1 + nbx(s[3] - s[2], B * CR_K), B, 0, stream>>>(
        nbN1, rr1, ev1, dis1, N_II,
        dst_uiu, cnt2, rank2, s[2], s[3]);

    // F4: g1 val+scatter | cnt2 slice 3
    f_valsc_cnt<<<nbN1 + nbx(s[4] - s[3], B * CR_K), B, 0, stream>>>(
        nbN1, rr1, dis1, brk1, gt1 + 1, ev1, perm1, rrp1, N_II,
        dst_uiu, cnt2, rank2, s[3], s[4]);

    // F5: g1 spmm layer1 | cnt2 slice 4
    f_spmm_cnt<<<nbS1 + nbx(s[5] - s[4], B * CR_K), B, 0, stream>>>(
        nbS1, rrp1, perm1, ev1, g1_x0, g1_x1, N_II,
        dst_uiu, cnt2, rank2, s[4], s[5]);

    // F6: g1 spmm layer2 | cnt2 slice 5 (cnt2 complete after this)
    f_spmm_cnt<<<nbS1 + nbx(s[6] - s[5], B * CR_K), B, 0, stream>>>(
        nbS1, rrp1, perm1, ev1, g1_x1, g1_x2, N_II,
        dst_uiu, cnt2, rank2, s[5], s[6]);

    // F7: g1 final (bf16 item rows -> hii_b) | g2 node
    f_final_node<<<nbS1 + nbN2, B, 0, stream>>>(
        nbS1, rrp1, perm1, ev1, g1_x2, g1_x1, g1_x0, nullptr, hii_b, alpha, N_II,
        cnt2, rr2, brk2, gt2 + 1, gt2, N_UIU);

    // g2 tail (serial dependencies)
    k_fillE<<<nbF2, B, 0, stream>>>(src_uiu, dst_uiu, w_uiu, rank2, rr2, ev2, E_UIU);
    k_deg  <<<nbN2, B, 0, stream>>>(rr2, ev2, dis2, N_UIU);
    k_valsc<<<nbN2, B, 0, stream>>>(rr2, dis2, brk2, gt2 + 1, ev2, perm2, rrp2, N_UIU);
    k_spmm8<<<nbS2, B, 0, stream>>>(rrp2, perm2, ev2, xb0_u, x1_u, N_UIU);
    k_spmm8<<<nbS2, B, 0, stream>>>(rrp2, perm2, ev2, x1_u, x2_u, N_UIU);
    k_spmm8_final<<<nbS2, B, 0, stream>>>(rrp2, perm2, ev2, x2_u, x1_u, xb0_u,
                                          (float4*)out, nullptr, alpha, N_UIU);
}